// Round 1
// baseline (655.695 us; speedup 1.0000x reference)
//
#include <hip/hip_runtime.h>

typedef float f32x4 __attribute__((ext_vector_type(4)));
typedef __bf16 bf16x8 __attribute__((ext_vector_type(8)));
typedef unsigned short u16x8 __attribute__((ext_vector_type(8)));

__device__ inline unsigned short f2bf(float f) {
  unsigned int u = __builtin_bit_cast(unsigned int, f);
  u += 0x7FFFu + ((u >> 16) & 1u);
  return (unsigned short)(u >> 16);
}

// ---------------- fp32 -> bf16 conversion ----------------
__global__ void cvtk(const float* __restrict__ in, unsigned short* __restrict__ out, int n) {
  int i = (blockIdx.x * blockDim.x + threadIdx.x) * 4;
  if (i < n) {
    float4 f = *(const float4*)(in + i);
    ushort4 o;
    o.x = f2bf(f.x); o.y = f2bf(f.y); o.z = f2bf(f.z); o.w = f2bf(f.w);
    *(ushort4*)(out + i) = o;
  }
}

// ---------------- GEMM: out[m][n] = sum_k A[m][k]*Bt[n][k] + bias[n] ----------------
// A: M x K bf16 row-major; Bt: N x K bf16 row-major.
// MODE 0: write bf16 scattered into [B,H,T,D] (B=4,H=16,T=2048,D=64), M=B*T, N=H*D
// MODE 1: write fp32 row-major M x N
#define GPITCH 88
template <int MODE>
__global__ __launch_bounds__(256) void gemm_bt(const unsigned short* __restrict__ A,
                                               const unsigned short* __restrict__ Bt,
                                               const float* __restrict__ bias,
                                               void* __restrict__ out,
                                               int M, int N, int K) {
  __shared__ __align__(16) unsigned short As[64 * GPITCH];
  __shared__ __align__(16) unsigned short Bs[64 * GPITCH];
  const int tid = threadIdx.x;
  const int lane = tid & 63, w = tid >> 6;
  const int quad = lane >> 4, l15 = lane & 15;
  const int wm = w & 1, wn = w >> 1;
  const int m0 = blockIdx.x * 64, n0 = blockIdx.y * 64;

  f32x4 acc[2][2] = {};

  for (int kb = 0; kb < K; kb += 64) {
#pragma unroll
    for (int i = 0; i < 2; i++) {
      int c = tid + i * 256;
      int row = c >> 3, col8 = (c & 7) * 8;
      *(uint4*)(As + row * GPITCH + col8) = *(const uint4*)(A + (size_t)(m0 + row) * K + kb + col8);
      *(uint4*)(Bs + row * GPITCH + col8) = *(const uint4*)(Bt + (size_t)(n0 + row) * K + kb + col8);
    }
    __syncthreads();
#pragma unroll
    for (int ks = 0; ks < 64; ks += 32) {
      bf16x8 a[2], bfr[2];
#pragma unroll
      for (int mt = 0; mt < 2; mt++)
        a[mt] = *(const bf16x8*)(As + (wm * 32 + mt * 16 + l15) * GPITCH + ks + quad * 8);
#pragma unroll
      for (int nt = 0; nt < 2; nt++)
        bfr[nt] = *(const bf16x8*)(Bs + (wn * 32 + nt * 16 + l15) * GPITCH + ks + quad * 8);
#pragma unroll
      for (int mt = 0; mt < 2; mt++)
#pragma unroll
        for (int nt = 0; nt < 2; nt++)
          acc[mt][nt] = __builtin_amdgcn_mfma_f32_16x16x32_bf16(a[mt], bfr[nt], acc[mt][nt], 0, 0, 0);
    }
    __syncthreads();
  }

#pragma unroll
  for (int mt = 0; mt < 2; mt++)
#pragma unroll
    for (int nt = 0; nt < 2; nt++) {
      int col = n0 + wn * 32 + nt * 16 + l15;
      float bv = bias[col];
#pragma unroll
      for (int r = 0; r < 4; r++) {
        int row = m0 + wm * 32 + mt * 16 + quad * 4 + r;
        float v = acc[mt][nt][r] + bv;
        if (MODE == 0) {
          int h = col >> 6, d = col & 63;
          int b = row >> 11, t = row & 2047;
          ((unsigned short*)out)[((size_t)((b * 16 + h) * 2048 + t)) * 64 + d] = f2bf(v);
        } else {
          ((float*)out)[(size_t)row * N + col] = v;
        }
      }
    }
}

// ---------------- Flash attention (causal), bf16 in/out, fp32 softmax ----------------
// Q,K,V: [B*H, T, D] bf16 (as ushort). Y: [B, T, H*D] bf16.
__global__ __launch_bounds__(256) void attn_kernel(const unsigned short* __restrict__ Q,
                                                   const unsigned short* __restrict__ Km,
                                                   const unsigned short* __restrict__ V,
                                                   unsigned short* __restrict__ Y) {
  constexpr int T = 2048, D = 64;
  constexpr int PP = 56;  // P LDS pitch (elems): 112B rows, 16B-aligned, 2-way banks
  __shared__ __align__(16) unsigned short P_lds[4][16 * PP];
  const int tid = threadIdx.x;
  const int lane = tid & 63, w = tid >> 6;
  const int quad = lane >> 4, l15 = lane & 15;
  const int bh = blockIdx.y;
  const int b = bh >> 4, h = bh & 15;
  const int qt = blockIdx.x * 64 + w * 16;  // this wave's 16-row q tile
  const unsigned short* Qp = Q + (size_t)bh * T * D;
  const unsigned short* Kp = Km + (size_t)bh * T * D;
  const unsigned short* Vp = V + (size_t)bh * T * D;

  bf16x8 aq[2];
  aq[0] = *(const bf16x8*)(Qp + (size_t)(qt + l15) * D + quad * 8);
  aq[1] = *(const bf16x8*)(Qp + (size_t)(qt + l15) * D + 32 + quad * 8);

  float mrow[4], lrow[4];
  f32x4 o[4] = {};
#pragma unroll
  for (int r = 0; r < 4; r++) { mrow[r] = -INFINITY; lrow[r] = 0.f; }

  for (int s0 = 0; s0 <= qt + 15; s0 += 32) {
    // ---- S = Q K^T (16 x 32 tile), fp32 acc ----
    f32x4 sacc[2] = {};
#pragma unroll
    for (int sc = 0; sc < 2; sc++)
#pragma unroll
      for (int kh = 0; kh < 2; kh++) {
        bf16x8 bk = *(const bf16x8*)(Kp + (size_t)(s0 + sc * 16 + l15) * D + kh * 32 + quad * 8);
        sacc[sc] = __builtin_amdgcn_mfma_f32_16x16x32_bf16(aq[kh], bk, sacc[sc], 0, 0, 0);
      }
    // ---- scale + causal mask + online softmax ----
    float p[2][4], tmax[4];
#pragma unroll
    for (int r = 0; r < 4; r++) tmax[r] = -INFINITY;
#pragma unroll
    for (int sc = 0; sc < 2; sc++) {
      int sg = s0 + sc * 16 + l15;
#pragma unroll
      for (int r = 0; r < 4; r++) {
        int qg = qt + quad * 4 + r;
        float v = sacc[sc][r] * 0.125f;
        v = (sg > qg) ? -INFINITY : v;
        p[sc][r] = v;
        tmax[r] = fmaxf(tmax[r], v);
      }
    }
#pragma unroll
    for (int off = 1; off < 16; off <<= 1)
#pragma unroll
      for (int r = 0; r < 4; r++) tmax[r] = fmaxf(tmax[r], __shfl_xor(tmax[r], off, 64));

    float alpha[4], rs[4];
#pragma unroll
    for (int r = 0; r < 4; r++) {
      float mnew = fmaxf(mrow[r], tmax[r]);
      alpha[r] = __expf(mrow[r] - mnew);
      mrow[r] = mnew;
      p[0][r] = __expf(p[0][r] - mnew);
      p[1][r] = __expf(p[1][r] - mnew);
      rs[r] = p[0][r] + p[1][r];
    }
#pragma unroll
    for (int off = 1; off < 16; off <<= 1)
#pragma unroll
      for (int r = 0; r < 4; r++) rs[r] += __shfl_xor(rs[r], off, 64);
#pragma unroll
    for (int r = 0; r < 4; r++) {
      lrow[r] = lrow[r] * alpha[r] + rs[r];
#pragma unroll
      for (int dc = 0; dc < 4; dc++) o[dc][r] *= alpha[r];
    }
    // ---- P: C-layout -> A-layout via per-wave LDS ----
    unsigned short* pl = P_lds[w];
#pragma unroll
    for (int sc = 0; sc < 2; sc++)
#pragma unroll
      for (int r = 0; r < 4; r++)
        pl[(quad * 4 + r) * PP + sc * 16 + l15] = f2bf(p[sc][r]);
    __asm__ __volatile__("" ::: "memory");  // keep LDS write->read ordered (same wave; HW DS is in-order)
    u16x8 apu = *(const u16x8*)(pl + l15 * PP + quad * 8);
    bf16x8 ap = __builtin_bit_cast(bf16x8, apu);
    // ---- O += P V ----
#pragma unroll
    for (int dc = 0; dc < 4; dc++) {
      u16x8 tv;
#pragma unroll
      for (int j = 0; j < 8; j++)
        tv[j] = Vp[(size_t)(s0 + quad * 8 + j) * D + dc * 16 + l15];
      bf16x8 bv = __builtin_bit_cast(bf16x8, tv);
      o[dc] = __builtin_amdgcn_mfma_f32_16x16x32_bf16(ap, bv, o[dc], 0, 0, 0);
    }
  }
  // ---- epilogue: O / l, write Y[b, t, h*64+d] ----
#pragma unroll
  for (int r = 0; r < 4; r++) {
    float inv = 1.f / lrow[r];
    int qg = qt + quad * 4 + r;
#pragma unroll
    for (int dc = 0; dc < 4; dc++)
      Y[((size_t)(b * T + qg)) * 1024 + h * 64 + dc * 16 + l15] = f2bf(o[dc][r] * inv);
  }
}

// ---------------- launch ----------------
extern "C" void kernel_launch(void* const* d_in, const int* in_sizes, int n_in,
                              void* d_out, int out_size, void* d_ws, size_t ws_size,
                              hipStream_t stream) {
  const float* x  = (const float*)d_in[0];
  const float* Wq = (const float*)d_in[1];
  const float* bq = (const float*)d_in[2];
  const float* Wk = (const float*)d_in[3];
  const float* bk = (const float*)d_in[4];
  const float* Wv = (const float*)d_in[5];
  const float* bv = (const float*)d_in[6];
  const float* Wp = (const float*)d_in[7];
  const float* bp = (const float*)d_in[8];

  const int NX = 4 * 2048 * 1024;  // 8388608
  const int NW = 1024 * 1024;      // 1048576

  char* ws = (char*)d_ws;
  unsigned short* xb  = (unsigned short*)(ws + 0);          // 16 MiB (reused as Y)
  unsigned short* wqb = (unsigned short*)(ws + 16777216);   // 2 MiB
  unsigned short* wkb = (unsigned short*)(ws + 18874368);
  unsigned short* wvb = (unsigned short*)(ws + 20971520);
  unsigned short* wpb = (unsigned short*)(ws + 23068672);
  unsigned short* Qb  = (unsigned short*)(ws + 25165824);   // 16 MiB each
  unsigned short* Kb  = (unsigned short*)(ws + 41943040);
  unsigned short* Vb  = (unsigned short*)(ws + 58720256);
  unsigned short* Yb  = xb;  // x no longer needed after QKV projections

  cvtk<<<NX / 4 / 256, 256, 0, stream>>>(x, xb, NX);
  cvtk<<<NW / 4 / 256, 256, 0, stream>>>(Wq, wqb, NW);
  cvtk<<<NW / 4 / 256, 256, 0, stream>>>(Wk, wkb, NW);
  cvtk<<<NW / 4 / 256, 256, 0, stream>>>(Wv, wvb, NW);
  cvtk<<<NW / 4 / 256, 256, 0, stream>>>(Wp, wpb, NW);

  dim3 gg(8192 / 64, 1024 / 64);
  gemm_bt<0><<<gg, 256, 0, stream>>>(xb, wqb, bq, Qb, 8192, 1024, 1024);
  gemm_bt<0><<<gg, 256, 0, stream>>>(xb, wkb, bk, Kb, 8192, 1024, 1024);
  gemm_bt<0><<<gg, 256, 0, stream>>>(xb, wvb, bv, Vb, 8192, 1024, 1024);

  attn_kernel<<<dim3(2048 / 64, 64), 256, 0, stream>>>(Qb, Kb, Vb, Yb);

  gemm_bt<1><<<gg, 256, 0, stream>>>(Yb, wpb, bp, d_out, 8192, 1024, 1024);
}

// Round 2
// 480.028 us; speedup vs baseline: 1.3660x; 1.3660x over previous
//
#include <hip/hip_runtime.h>

typedef float f32x4 __attribute__((ext_vector_type(4)));
typedef __bf16 bf16x8 __attribute__((ext_vector_type(8)));
typedef unsigned short u16x8 __attribute__((ext_vector_type(8)));

__device__ inline unsigned short f2bf(float f) {
  unsigned int u = __builtin_bit_cast(unsigned int, f);
  u += 0x7FFFu + ((u >> 16) & 1u);
  return (unsigned short)(u >> 16);
}

// DPP rotate within 16-lane row (VALU pipe, avoids ds_swizzle on LDS pipe)
template <int N>
__device__ inline float rowror(float v) {
  return __builtin_bit_cast(float, __builtin_amdgcn_update_dpp(
      0, __builtin_bit_cast(int, v), 0x120 | N, 0xF, 0xF, true));
}
__device__ inline float rowmax16(float v) {
  v = fmaxf(v, rowror<8>(v)); v = fmaxf(v, rowror<4>(v));
  v = fmaxf(v, rowror<2>(v)); v = fmaxf(v, rowror<1>(v));
  return v;
}
__device__ inline float rowsum16(float v) {
  v += rowror<8>(v); v += rowror<4>(v);
  v += rowror<2>(v); v += rowror<1>(v);
  return v;
}

__device__ inline void gload_lds16(const unsigned short* g, unsigned short* l) {
  __builtin_amdgcn_global_load_lds(
      (const __attribute__((address_space(1))) unsigned int*)g,
      (__attribute__((address_space(3))) unsigned int*)l, 16, 0, 0);
}

// ---------------- fp32 -> bf16 conversion ----------------
__global__ void cvt_x(const float* __restrict__ in, unsigned short* __restrict__ out) {
  int i = (blockIdx.x * 256 + threadIdx.x) * 4;
  float4 f = *(const float4*)(in + i);
  ushort4 o;
  o.x = f2bf(f.x); o.y = f2bf(f.y); o.z = f2bf(f.z); o.w = f2bf(f.w);
  *(ushort4*)(out + i) = o;
}

__global__ void cvt_w(const float* __restrict__ a, const float* __restrict__ b,
                      const float* __restrict__ c, const float* __restrict__ d,
                      unsigned short* __restrict__ oa, unsigned short* __restrict__ ob,
                      unsigned short* __restrict__ oc, unsigned short* __restrict__ od) {
  const float* src[4] = {a, b, c, d};
  unsigned short* dst[4] = {oa, ob, oc, od};
  int m = blockIdx.y;
  int i = (blockIdx.x * 256 + threadIdx.x) * 4;
  float4 f = *(const float4*)(src[m] + i);
  ushort4 o;
  o.x = f2bf(f.x); o.y = f2bf(f.y); o.z = f2bf(f.z); o.w = f2bf(f.w);
  *(ushort4*)(dst[m] + i) = o;
}

// ---------------- GEMM: out[m][n] = sum_k A[m][k]*Bt[n][k] + bias[n] ----------------
// 128x128 tile, BK=64, global_load_lds width16, XOR-swizzled chunk layout
// (swizzle applied on global source side; LDS dest is lane-contiguous).
// MODE 0: bf16 scatter into [B,H,T,D]; MODE 1: fp32 row-major MxN.
template <int MODE>
__global__ __launch_bounds__(256) void gemm128(const unsigned short* __restrict__ A,
                                               const unsigned short* __restrict__ Bt,
                                               const float* __restrict__ bias,
                                               void* __restrict__ out,
                                               int M, int N, int K) {
  __shared__ __align__(16) unsigned short As[128 * 64];
  __shared__ __align__(16) unsigned short Bs[128 * 64];
  const int tid = threadIdx.x;
  const int lane = tid & 63, w = tid >> 6;
  const int quad = lane >> 4, l15 = lane & 15;
  const int wm = w & 1, wn = w >> 1;
  const int m0 = blockIdx.x * 128, n0 = blockIdx.y * 128;

  f32x4 acc[4][4] = {};

  for (int kb = 0; kb < K; kb += 64) {
#pragma unroll
    for (int j = 0; j < 4; j++) {
      int ch = j * 256 + w * 64 + lane;          // chunk id 0..1023
      int row = ch >> 3, pc = ch & 7;            // phys chunk col
      int c = pc ^ (row & 7);                    // logical (global) chunk col
      gload_lds16(A + (size_t)(m0 + row) * K + kb + c * 8, As + (size_t)(j * 256 + w * 64) * 8);
      gload_lds16(Bt + (size_t)(n0 + row) * K + kb + c * 8, Bs + (size_t)(j * 256 + w * 64) * 8);
    }
    __syncthreads();
#pragma unroll
    for (int ks = 0; ks < 64; ks += 32) {
      bf16x8 af[4], bf[4];
#pragma unroll
      for (int mt = 0; mt < 4; mt++) {
        int row = wm * 64 + mt * 16 + l15;
        int pc = ((ks >> 3) + quad) ^ (row & 7);
        af[mt] = *(const bf16x8*)(As + row * 64 + pc * 8);
      }
#pragma unroll
      for (int nt = 0; nt < 4; nt++) {
        int row = wn * 64 + nt * 16 + l15;
        int pc = ((ks >> 3) + quad) ^ (row & 7);
        bf[nt] = *(const bf16x8*)(Bs + row * 64 + pc * 8);
      }
#pragma unroll
      for (int mt = 0; mt < 4; mt++)
#pragma unroll
        for (int nt = 0; nt < 4; nt++)
          acc[mt][nt] = __builtin_amdgcn_mfma_f32_16x16x32_bf16(af[mt], bf[nt], acc[mt][nt], 0, 0, 0);
    }
    __syncthreads();
  }

#pragma unroll
  for (int mt = 0; mt < 4; mt++)
#pragma unroll
    for (int nt = 0; nt < 4; nt++) {
      int col = n0 + wn * 64 + nt * 16 + l15;
      float bv = bias[col];
#pragma unroll
      for (int r = 0; r < 4; r++) {
        int row = m0 + wm * 64 + mt * 16 + quad * 4 + r;
        float v = acc[mt][nt][r] + bv;
        if (MODE == 0) {
          int h = col >> 6, d = col & 63;
          int b = row >> 11, t = row & 2047;
          ((unsigned short*)out)[((size_t)((b * 16 + h) * 2048 + t)) * 64 + d] = f2bf(v);
        } else {
          ((float*)out)[(size_t)row * N + col] = v;
        }
      }
    }
}

// ---------------- V transpose: V[bh][t][d] -> Vt[bh][d][t] ----------------
__global__ __launch_bounds__(256) void transpose_v(const unsigned short* __restrict__ V,
                                                   unsigned short* __restrict__ Vt) {
  constexpr int P = 66;  // pad: bank = (t + d/2) % 32 on column reads
  __shared__ unsigned short L[64 * P];
  const int tid = threadIdx.x;
  const int bh = blockIdx.y;
  const int t0 = blockIdx.x * 64;
  const unsigned short* Vp = V + (size_t)bh * 2048 * 64;
  unsigned short* Op = Vt + (size_t)bh * 64 * 2048;
#pragma unroll
  for (int j = 0; j < 2; j++) {
    int r = (tid >> 3) + j * 32;
    int c = (tid & 7) * 8;
    u16x8 v = *(const u16x8*)(Vp + (size_t)(t0 + r) * 64 + c);
#pragma unroll
    for (int i = 0; i < 4; i++) {
      unsigned int pk = (unsigned int)v[2 * i] | ((unsigned int)v[2 * i + 1] << 16);
      *(unsigned int*)&L[r * P + c + 2 * i] = pk;
    }
  }
  __syncthreads();
#pragma unroll
  for (int j = 0; j < 2; j++) {
    int ch = j * 256 + tid;
    int d = ch >> 3, tc = (ch & 7) * 8;
    u16x8 o;
#pragma unroll
    for (int k = 0; k < 8; k++) o[k] = L[(tc + k) * P + d];
    *(u16x8*)(Op + (size_t)d * 2048 + t0 + tc) = o;
  }
}

// ---------------- Flash attention (causal), work-balanced, Vt layout ----------------
// Q,K: [B*H, T, D] bf16; Vt: [B*H, D, T] bf16; Y: [B, T, H*D] bf16.
// Block p handles Q 32-row tiles p and 63-p (uniform work per block).
__global__ __launch_bounds__(256) void attn_kernel(const unsigned short* __restrict__ Q,
                                                   const unsigned short* __restrict__ Km,
                                                   const unsigned short* __restrict__ Vt,
                                                   unsigned short* __restrict__ Y) {
  constexpr int T = 2048, D = 64;
  constexpr int PP = 72;  // P LDS pitch: 144B rows, 16B-aligned
  __shared__ __align__(16) unsigned short P_lds[4][16 * PP];
  const int tid = threadIdx.x;
  const int lane = tid & 63, w = tid >> 6;
  const int quad = lane >> 4, l15 = lane & 15;
  const int bh = blockIdx.y;
  const int b = bh >> 4, h = bh & 15;
  const int pr = blockIdx.x;
  const int qt = (w < 2) ? (pr * 32 + w * 16) : ((63 - pr) * 32 + (w - 2) * 16);
  const unsigned short* Qp = Q + (size_t)bh * T * D;
  const unsigned short* Kp = Km + (size_t)bh * T * D;
  const unsigned short* Vp = Vt + (size_t)bh * D * T;  // [d][t]

  bf16x8 aq[2];
  aq[0] = *(const bf16x8*)(Qp + (size_t)(qt + l15) * D + quad * 8);
  aq[1] = *(const bf16x8*)(Qp + (size_t)(qt + l15) * D + 32 + quad * 8);

  float mrow[4], lrow[4];
  f32x4 o[4] = {};
#pragma unroll
  for (int r = 0; r < 4; r++) { mrow[r] = -INFINITY; lrow[r] = 0.f; }

  const int send = qt + 15;
  unsigned short* pl = P_lds[w];

  for (int s0 = 0; s0 <= send; s0 += 64) {
    const int nsc = min(4, ((send - s0) >> 4) + 1);  // active 16-col subtiles
    const int nsc2 = (nsc + 1) & ~1;                 // rounded to PV half-granularity

    float p4[4][4];
    float tmax[4] = {-INFINITY, -INFINITY, -INFINITY, -INFINITY};
#pragma unroll
    for (int sc = 0; sc < 4; sc++) {
      if (sc < nsc) {
        f32x4 s = {};
#pragma unroll
        for (int kh = 0; kh < 2; kh++) {
          u16x8 bku = *(const u16x8*)(Kp + (size_t)(s0 + sc * 16 + l15) * D + kh * 32 + quad * 8);
          s = __builtin_amdgcn_mfma_f32_16x16x32_bf16(aq[kh], __builtin_bit_cast(bf16x8, bku), s, 0, 0, 0);
        }
        int sg = s0 + sc * 16 + l15;
#pragma unroll
        for (int r = 0; r < 4; r++) {
          int qg = qt + quad * 4 + r;
          float v = s[r] * 0.125f;
          v = (sg > qg) ? -INFINITY : v;
          p4[sc][r] = v;
          tmax[r] = fmaxf(tmax[r], v);
        }
      }
    }
#pragma unroll
    for (int r = 0; r < 4; r++) tmax[r] = rowmax16(tmax[r]);

    float alpha[4], rs[4];
#pragma unroll
    for (int r = 0; r < 4; r++) {
      float mnew = fmaxf(mrow[r], tmax[r]);
      alpha[r] = __expf(mrow[r] - mnew);
      mrow[r] = mnew;
      float a0 = 0.f;
#pragma unroll
      for (int sc = 0; sc < 4; sc++)
        if (sc < nsc) { p4[sc][r] = __expf(p4[sc][r] - mnew); a0 += p4[sc][r]; }
      rs[r] = a0;
    }
#pragma unroll
    for (int r = 0; r < 4; r++) rs[r] = rowsum16(rs[r]);
#pragma unroll
    for (int r = 0; r < 4; r++) {
      lrow[r] = lrow[r] * alpha[r] + rs[r];
#pragma unroll
      for (int dc = 0; dc < 4; dc++) o[dc][r] *= alpha[r];
    }

    // P: C-layout -> A-layout via per-wave LDS (zero-fill masked subtiles)
#pragma unroll
    for (int sc = 0; sc < 4; sc++) {
      if (sc < nsc) {
#pragma unroll
        for (int r = 0; r < 4; r++)
          pl[(quad * 4 + r) * PP + sc * 16 + l15] = f2bf(p4[sc][r]);
      } else if (sc < nsc2) {
#pragma unroll
        for (int r = 0; r < 4; r++)
          pl[(quad * 4 + r) * PP + sc * 16 + l15] = 0;
      }
    }
    __asm__ __volatile__("" ::: "memory");
    // O += P V  (per 32-col half)
#pragma unroll
    for (int h2 = 0; h2 < 2; h2++) {
      if (h2 * 2 < nsc2) {
        u16x8 apu = *(const u16x8*)(pl + l15 * PP + h2 * 32 + quad * 8);
        bf16x8 ap = __builtin_bit_cast(bf16x8, apu);
#pragma unroll
        for (int dc = 0; dc < 4; dc++) {
          u16x8 vu = *(const u16x8*)(Vp + (size_t)(dc * 16 + l15) * T + s0 + h2 * 32 + quad * 8);
          o[dc] = __builtin_amdgcn_mfma_f32_16x16x32_bf16(ap, __builtin_bit_cast(bf16x8, vu), o[dc], 0, 0, 0);
        }
      }
    }
  }

#pragma unroll
  for (int r = 0; r < 4; r++) {
    float inv = 1.f / lrow[r];
    int qg = qt + quad * 4 + r;
#pragma unroll
    for (int dc = 0; dc < 4; dc++)
      Y[((size_t)(b * T + qg)) * 1024 + h * 64 + dc * 16 + l15] = f2bf(o[dc][r] * inv);
  }
}

// ---------------- launch ----------------
extern "C" void kernel_launch(void* const* d_in, const int* in_sizes, int n_in,
                              void* d_out, int out_size, void* d_ws, size_t ws_size,
                              hipStream_t stream) {
  const float* x  = (const float*)d_in[0];
  const float* Wq = (const float*)d_in[1];
  const float* bq = (const float*)d_in[2];
  const float* Wk = (const float*)d_in[3];
  const float* bk = (const float*)d_in[4];
  const float* Wv = (const float*)d_in[5];
  const float* bv = (const float*)d_in[6];
  const float* Wp = (const float*)d_in[7];
  const float* bp = (const float*)d_in[8];

  char* ws = (char*)d_ws;
  unsigned short* xb  = (unsigned short*)(ws + 0);          // 16 MiB: x bf16; later Vt
  unsigned short* wqb = (unsigned short*)(ws + 16777216);   // 2 MiB each
  unsigned short* wkb = (unsigned short*)(ws + 18874368);
  unsigned short* wvb = (unsigned short*)(ws + 20971520);
  unsigned short* wpb = (unsigned short*)(ws + 23068672);
  unsigned short* Qb  = (unsigned short*)(ws + 25165824);   // 16 MiB each
  unsigned short* Kb  = (unsigned short*)(ws + 41943040);
  unsigned short* Vb  = (unsigned short*)(ws + 58720256);
  unsigned short* Vtb = xb;  // x dead after QKV GEMMs
  unsigned short* Yb  = Vb;  // V dead after transpose

  cvt_x<<<8192, 256, 0, stream>>>(x, xb);
  cvt_w<<<dim3(1024, 4), 256, 0, stream>>>(Wq, Wk, Wv, Wp, wqb, wkb, wvb, wpb);

  dim3 gg(64, 8);
  gemm128<0><<<gg, 256, 0, stream>>>(xb, wqb, bq, Qb, 8192, 1024, 1024);
  gemm128<0><<<gg, 256, 0, stream>>>(xb, wkb, bk, Kb, 8192, 1024, 1024);
  gemm128<0><<<gg, 256, 0, stream>>>(xb, wvb, bv, Vb, 8192, 1024, 1024);

  transpose_v<<<dim3(32, 64), 256, 0, stream>>>(Vb, Vtb);
  attn_kernel<<<dim3(32, 64), 256, 0, stream>>>(Qb, Kb, Vtb, Yb);

  gemm128<1><<<gg, 256, 0, stream>>>(Yb, wpb, bp, d_out, 8192, 1024, 1024);
}